// Round 2
// baseline (69.640 us; speedup 1.0000x reference)
//
#include <hip/hip_runtime.h>
#include <hip/hip_bf16.h>

#define NNODES 100000
#define DIMF   128
#define NB     32768
#define KNEI   25
#define UNITS  128
#define KDIM   256   // 2*DIMF
#define BM     16    // rows per block

typedef __bf16 bf16x8 __attribute__((ext_vector_type(8)));
typedef float  f32x4  __attribute__((ext_vector_type(4)));

__device__ __forceinline__ unsigned short bf16u(float x) {
    __hip_bfloat16 h = __float2bfloat16(x);
    return __builtin_bit_cast(unsigned short, h);
}

// Convert W (256x128 f32, row-major) -> Wt (128x256 bf16, row-major = W^T)
__global__ void wconv_kernel(const float* __restrict__ W,
                             unsigned short* __restrict__ Wt) {
    int i = blockIdx.x * 256 + threadIdx.x;   // 0..32767
    int n = i >> 8;                           // 0..127 (output unit)
    int k = i & 255;                          // 0..255 (concat dim)
    Wt[n * KDIM + k] = bf16u(W[k * UNITS + n]);
}

// Fused gather+mean+GEMM+relu. BM=16 rows per block, 256 threads (4 waves).
// Grid 2048 -> 8 blocks/CU -> 32 waves/CU (100% occupancy potential).
__global__ __launch_bounds__(256) void fused_kernel(
    const float* __restrict__ features,
    const int*   __restrict__ node,
    const int*   __restrict__ neigh,
    const unsigned short* __restrict__ Wt,
    float* __restrict__ out)
{
    __shared__ unsigned short lds[BM * KDIM];   // 8 KB, XOR-swizzled concat tile (bf16)

    const int tid = threadIdx.x;
    const int blk = blockIdx.x;

    // ---------------- Phase 1: gather + mean -> LDS (bf16) ----------------
    // 32 lanes per row: lane4 covers dims [lane4*4, lane4*4+4)
    const int lane4 = tid & 31;
    const int rgrp  = tid >> 5;                 // 0..7 (8 rows in flight)
    const float4* feat4 = (const float4*)features;

    #pragma unroll
    for (int rr = 0; rr < 2; ++rr) {
        const int row = rr * 8 + rgrp;          // 0..15
        const int g   = blk * BM + row;         // global output row

        const int nidx = node[g];
        float4 nf = feat4[(size_t)nidx * 32 + lane4];

        float4 acc; acc.x = 0.f; acc.y = 0.f; acc.z = 0.f; acc.w = 0.f;
        const int* nb = neigh + (size_t)g * KNEI;
        #pragma unroll
        for (int k = 0; k < KNEI; ++k) {
            const int idx = nb[k];
            float4 v = feat4[(size_t)idx * 32 + lane4];
            acc.x += v.x; acc.y += v.y; acc.z += v.z; acc.w += v.w;
        }
        const float s = 1.0f / 25.0f;
        acc.x *= s; acc.y *= s; acc.z *= s; acc.w *= s;

        // pack node half (cols lane4*4 .. +3)
        ushort4 pn; pn.x = bf16u(nf.x); pn.y = bf16u(nf.y); pn.z = bf16u(nf.z); pn.w = bf16u(nf.w);
        int off0 = (row * 512 + lane4 * 8) ^ ((row & 7) << 4);
        *(ushort4*)((char*)lds + off0) = pn;

        // pack mean half (cols 128 + lane4*4 .. +3)
        ushort4 pm; pm.x = bf16u(acc.x); pm.y = bf16u(acc.y); pm.z = bf16u(acc.z); pm.w = bf16u(acc.w);
        int off1 = (row * 512 + 256 + lane4 * 8) ^ ((row & 7) << 4);
        *(ushort4*)((char*)lds + off1) = pm;
    }

    __syncthreads();

    // ---------------- Phase 2: MFMA GEMM (16x256 bf16) x (256x128 bf16) ----------------
    const int wv     = tid >> 6;                // 0..3 -> 32-col slice
    const int lane   = tid & 63;
    const int l15    = lane & 15;
    const int khalf  = lane >> 4;               // 0..3
    const int colbase = wv * 32;

    f32x4 acc00 = {0.f,0.f,0.f,0.f};
    f32x4 acc01 = {0.f,0.f,0.f,0.f};

    #pragma unroll
    for (int ks = 0; ks < 8; ++ks) {
        const int ke = ks * 32 + khalf * 8;     // starting k element for this lane (8 elems)

        // A fragment from swizzled LDS (row = m index, 8 consecutive k)
        const int row0  = l15;
        const int byte0 = (row0 * 512 + ke * 2) ^ ((row0 & 7) << 4);
        bf16x8 a0 = *(const bf16x8*)((const char*)lds + byte0);

        // B fragments from Wt (row = n index, 8 consecutive k) — L2-resident
        bf16x8 b0 = *(const bf16x8*)(Wt + (size_t)(colbase + l15)      * KDIM + ke);
        bf16x8 b1 = *(const bf16x8*)(Wt + (size_t)(colbase + 16 + l15) * KDIM + ke);

        acc00 = __builtin_amdgcn_mfma_f32_16x16x32_bf16(a0, b0, acc00, 0, 0, 0);
        acc01 = __builtin_amdgcn_mfma_f32_16x16x32_bf16(a0, b1, acc01, 0, 0, 0);
    }

    // ---------------- Epilogue: relu + store ----------------
    // C/D layout: col = lane&15, row = (lane>>4)*4 + i   [m89-verified]
    #pragma unroll
    for (int i = 0; i < 4; ++i) {
        const int r0 = blk * BM + khalf * 4 + i;
        const int c0 = colbase + l15;
        const int c1 = c0 + 16;
        out[(size_t)r0 * UNITS + c0] = fmaxf(acc00[i], 0.f);
        out[(size_t)r0 * UNITS + c1] = fmaxf(acc01[i], 0.f);
    }
}

extern "C" void kernel_launch(void* const* d_in, const int* in_sizes, int n_in,
                              void* d_out, int out_size, void* d_ws, size_t ws_size,
                              hipStream_t stream) {
    const float* features = (const float*)d_in[0];
    const int*   node     = (const int*)d_in[1];
    const int*   neigh    = (const int*)d_in[2];
    const float* W        = (const float*)d_in[3];
    float* out            = (float*)d_out;
    unsigned short* Wt    = (unsigned short*)d_ws;   // 128*256*2 = 64 KB

    wconv_kernel<<<128, 256, 0, stream>>>(W, Wt);
    fused_kernel<<<NB / BM, 256, 0, stream>>>(features, node, neigh, Wt, out);
}

// Round 3
// 56.335 us; speedup vs baseline: 1.2362x; 1.2362x over previous
//
#include <hip/hip_runtime.h>
#include <hip/hip_bf16.h>

#define NNODES 100000
#define DIMF   128
#define NB     32768
#define KNEI   25
#define UNITS  128
#define KDIM   256   // 2*DIMF
#define BM     16    // rows per block

typedef __bf16 bf16x8 __attribute__((ext_vector_type(8)));
typedef float  f32x4  __attribute__((ext_vector_type(4)));
typedef unsigned short u16x8 __attribute__((ext_vector_type(8)));

__device__ __forceinline__ unsigned short bf16u(float x) {
    __hip_bfloat16 h = __float2bfloat16(x);
    return __builtin_bit_cast(unsigned short, h);
}

// Convert W (256x128 f32, row-major) -> Wt (128x256 bf16, row-major = W^T)
__global__ void wconv_kernel(const float* __restrict__ W,
                             unsigned short* __restrict__ Wt) {
    int i = blockIdx.x * 256 + threadIdx.x;   // 0..32767
    int n = i >> 8;                           // 0..127 (output unit)
    int k = i & 255;                          // 0..255 (concat dim)
    Wt[n * KDIM + k] = bf16u(W[k * UNITS + n]);
}

// Convert features (100000x128 f32) -> bf16 table. 8 elems/thread.
__global__ __launch_bounds__(256) void fconv_kernel(const float* __restrict__ F,
                                                    unsigned short* __restrict__ T) {
    int i = blockIdx.x * 256 + threadIdx.x;   // 0..1,599,999
    const float4* f4 = (const float4*)F;
    float4 a = f4[(size_t)i * 2];
    float4 b = f4[(size_t)i * 2 + 1];
    u16x8 o;
    o[0] = bf16u(a.x); o[1] = bf16u(a.y); o[2] = bf16u(a.z); o[3] = bf16u(a.w);
    o[4] = bf16u(b.x); o[5] = bf16u(b.y); o[6] = bf16u(b.z); o[7] = bf16u(b.w);
    *(u16x8*)(T + (size_t)i * 8) = o;
}

// ---------------- bf16-table fused kernel ----------------
// BM=16 rows/block, 256 threads. 16 lanes per row (16B bf16x8 per lane).
__global__ __launch_bounds__(256) void fused_bf16_kernel(
    const unsigned short* __restrict__ ftab,   // bf16 features [NNODES][DIMF]
    const int*   __restrict__ node,
    const int*   __restrict__ neigh,
    const unsigned short* __restrict__ Wt,
    float* __restrict__ out)
{
    __shared__ unsigned short lds[BM * KDIM];   // 8 KB, XOR-swizzled concat tile

    const int tid = threadIdx.x;
    const int blk = blockIdx.x;

    // ---------------- Phase 1: gather + mean -> LDS ----------------
    const int lane8 = tid & 15;                 // dims [lane8*8, lane8*8+8)
    const int row   = tid >> 4;                 // 0..15
    const int g     = blk * BM + row;

    // node half: already bf16, straight to LDS
    const int nidx = node[g];
    u16x8 nf = *(const u16x8*)(ftab + (size_t)nidx * DIMF + lane8 * 8);
    const int off0 = (row * 512 + lane8 * 16) ^ ((row & 7) << 4);
    *(u16x8*)((char*)lds + off0) = nf;

    // neighbor mean: accumulate f32
    float acc[8];
    #pragma unroll
    for (int j = 0; j < 8; ++j) acc[j] = 0.f;
    const int* nb = neigh + (size_t)g * KNEI;
    #pragma unroll
    for (int k = 0; k < KNEI; ++k) {
        u16x8 v = *(const u16x8*)(ftab + (size_t)nb[k] * DIMF + lane8 * 8);
        #pragma unroll
        for (int j = 0; j < 8; ++j) {
            unsigned int u = ((unsigned int)v[j]) << 16;
            acc[j] += __builtin_bit_cast(float, u);
        }
    }
    u16x8 pm;
    const float s = 1.0f / 25.0f;
    #pragma unroll
    for (int j = 0; j < 8; ++j) pm[j] = bf16u(acc[j] * s);
    const int off1 = (row * 512 + 256 + lane8 * 16) ^ ((row & 7) << 4);
    *(u16x8*)((char*)lds + off1) = pm;

    __syncthreads();

    // ---------------- Phase 2: MFMA GEMM (16x256) x (256x128) ----------------
    const int wv      = tid >> 6;               // 0..3 -> 32-col slice
    const int lane    = tid & 63;
    const int l15     = lane & 15;
    const int khalf   = lane >> 4;              // 0..3
    const int colbase = wv * 32;

    f32x4 acc00 = {0.f,0.f,0.f,0.f};
    f32x4 acc01 = {0.f,0.f,0.f,0.f};

    #pragma unroll
    for (int ks = 0; ks < 8; ++ks) {
        const int ke = ks * 32 + khalf * 8;

        const int row0  = l15;
        const int byte0 = (row0 * 512 + ke * 2) ^ ((row0 & 7) << 4);
        bf16x8 a0 = *(const bf16x8*)((const char*)lds + byte0);

        bf16x8 b0 = *(const bf16x8*)(Wt + (size_t)(colbase + l15)      * KDIM + ke);
        bf16x8 b1 = *(const bf16x8*)(Wt + (size_t)(colbase + 16 + l15) * KDIM + ke);

        acc00 = __builtin_amdgcn_mfma_f32_16x16x32_bf16(a0, b0, acc00, 0, 0, 0);
        acc01 = __builtin_amdgcn_mfma_f32_16x16x32_bf16(a0, b1, acc01, 0, 0, 0);
    }

    #pragma unroll
    for (int i = 0; i < 4; ++i) {
        const int r0 = blk * BM + khalf * 4 + i;
        const int c0 = colbase + l15;
        const int c1 = c0 + 16;
        out[(size_t)r0 * UNITS + c0] = fmaxf(acc00[i], 0.f);
        out[(size_t)r0 * UNITS + c1] = fmaxf(acc01[i], 0.f);
    }
}

// ---------------- fallback f32-gather fused kernel (if ws too small) ----------------
__global__ __launch_bounds__(256) void fused_kernel(
    const float* __restrict__ features,
    const int*   __restrict__ node,
    const int*   __restrict__ neigh,
    const unsigned short* __restrict__ Wt,
    float* __restrict__ out)
{
    __shared__ unsigned short lds[BM * KDIM];

    const int tid = threadIdx.x;
    const int blk = blockIdx.x;

    const int lane4 = tid & 31;
    const int rgrp  = tid >> 5;
    const float4* feat4 = (const float4*)features;

    #pragma unroll
    for (int rr = 0; rr < 2; ++rr) {
        const int row = rr * 8 + rgrp;
        const int g   = blk * BM + row;

        const int nidx = node[g];
        float4 nf = feat4[(size_t)nidx * 32 + lane4];

        float4 acc; acc.x = 0.f; acc.y = 0.f; acc.z = 0.f; acc.w = 0.f;
        const int* nb = neigh + (size_t)g * KNEI;
        #pragma unroll
        for (int k = 0; k < KNEI; ++k) {
            const int idx = nb[k];
            float4 v = feat4[(size_t)idx * 32 + lane4];
            acc.x += v.x; acc.y += v.y; acc.z += v.z; acc.w += v.w;
        }
        const float s = 1.0f / 25.0f;
        acc.x *= s; acc.y *= s; acc.z *= s; acc.w *= s;

        ushort4 pn; pn.x = bf16u(nf.x); pn.y = bf16u(nf.y); pn.z = bf16u(nf.z); pn.w = bf16u(nf.w);
        int off0 = (row * 512 + lane4 * 8) ^ ((row & 7) << 4);
        *(ushort4*)((char*)lds + off0) = pn;

        ushort4 pm; pm.x = bf16u(acc.x); pm.y = bf16u(acc.y); pm.z = bf16u(acc.z); pm.w = bf16u(acc.w);
        int off1 = (row * 512 + 256 + lane4 * 8) ^ ((row & 7) << 4);
        *(ushort4*)((char*)lds + off1) = pm;
    }

    __syncthreads();

    const int wv      = tid >> 6;
    const int lane    = tid & 63;
    const int l15     = lane & 15;
    const int khalf   = lane >> 4;
    const int colbase = wv * 32;

    f32x4 acc00 = {0.f,0.f,0.f,0.f};
    f32x4 acc01 = {0.f,0.f,0.f,0.f};

    #pragma unroll
    for (int ks = 0; ks < 8; ++ks) {
        const int ke = ks * 32 + khalf * 8;

        const int row0  = l15;
        const int byte0 = (row0 * 512 + ke * 2) ^ ((row0 & 7) << 4);
        bf16x8 a0 = *(const bf16x8*)((const char*)lds + byte0);

        bf16x8 b0 = *(const bf16x8*)(Wt + (size_t)(colbase + l15)      * KDIM + ke);
        bf16x8 b1 = *(const bf16x8*)(Wt + (size_t)(colbase + 16 + l15) * KDIM + ke);

        acc00 = __builtin_amdgcn_mfma_f32_16x16x32_bf16(a0, b0, acc00, 0, 0, 0);
        acc01 = __builtin_amdgcn_mfma_f32_16x16x32_bf16(a0, b1, acc01, 0, 0, 0);
    }

    #pragma unroll
    for (int i = 0; i < 4; ++i) {
        const int r0 = blk * BM + khalf * 4 + i;
        const int c0 = colbase + l15;
        const int c1 = c0 + 16;
        out[(size_t)r0 * UNITS + c0] = fmaxf(acc00[i], 0.f);
        out[(size_t)r0 * UNITS + c1] = fmaxf(acc01[i], 0.f);
    }
}

extern "C" void kernel_launch(void* const* d_in, const int* in_sizes, int n_in,
                              void* d_out, int out_size, void* d_ws, size_t ws_size,
                              hipStream_t stream) {
    const float* features = (const float*)d_in[0];
    const int*   node     = (const int*)d_in[1];
    const int*   neigh    = (const int*)d_in[2];
    const float* W        = (const float*)d_in[3];
    float* out            = (float*)d_out;

    unsigned short* Wt = (unsigned short*)d_ws;                    // 64 KB
    const size_t ftab_off   = 65536;
    const size_t ftab_bytes = (size_t)NNODES * DIMF * 2;           // 25.6 MB
    const bool   use_bf16   = ws_size >= ftab_off + ftab_bytes;

    wconv_kernel<<<128, 256, 0, stream>>>(W, Wt);

    if (use_bf16) {
        unsigned short* ftab = (unsigned short*)((char*)d_ws + ftab_off);
        // 100000*128 / (256*8) = 6250 blocks exactly
        fconv_kernel<<<6250, 256, 0, stream>>>(features, ftab);
        fused_bf16_kernel<<<NB / BM, 256, 0, stream>>>(ftab, node, neigh, Wt, out);
    } else {
        fused_kernel<<<NB / BM, 256, 0, stream>>>(features, node, neigh, Wt, out);
    }
}